// Round 3
// baseline (802.685 us; speedup 1.0000x reference)
//
#include <hip/hip_runtime.h>
#include <hip/hip_bf16.h>
#include <stdint.h>

#define NE 131072
#define CHUNK 32768

typedef __attribute__((ext_vector_type(8))) short bf16x8;
typedef __attribute__((ext_vector_type(4))) float f32x4;

__device__ __forceinline__ unsigned short f2bf(float f) {
  unsigned u = __float_as_uint(f);
  u += 0x7FFF + ((u >> 16) & 1);   // round-to-nearest-even
  return (unsigned short)(u >> 16);
}
__device__ __forceinline__ float bf2f(unsigned short h) {
  return __uint_as_float((unsigned)h << 16);
}

__device__ __forceinline__ void gload_lds16(const void* g, void* l) {
  __builtin_amdgcn_global_load_lds(
      (const __attribute__((address_space(1))) unsigned*)g,
      (__attribute__((address_space(3))) unsigned*)l, 16, 0, 0);
}

// dst[p][n][k] = bf16(src[p][k][n]);  src fp32 [P][K][Nc], dst bf16 [P][Nc][K]
__global__ void transpose_cvt(const float* __restrict__ src,
                              unsigned short* __restrict__ dst,
                              int K, int Nc) {
  int p = blockIdx.y;
  long base = (long)p * K * Nc;
  int tot = K * Nc;
  for (int i = blockIdx.x * blockDim.x + threadIdx.x; i < tot;
       i += gridDim.x * blockDim.x) {
    int n = i / K, k = i - n * K;
    dst[base + i] = f2bf(src[base + (long)k * Nc + n]);
  }
}

__global__ void relu_cvt_x(const float4* __restrict__ x,
                           ushort4* __restrict__ xb) {
  int i = blockIdx.x * blockDim.x + threadIdx.x;
  float4 v = x[i];
  ushort4 o;
  o.x = f2bf(fmaxf(v.x, 0.f));
  o.y = f2bf(fmaxf(v.y, 0.f));
  o.z = f2bf(fmaxf(v.z, 0.f));
  o.w = f2bf(fmaxf(v.w, 0.f));
  xb[i] = o;
}

// ---- m97-structure 128x128 kernel, used only for L0 (K=64) ----
__global__ __launch_bounds__(256, 2) void gemm_bf16(
    const unsigned short* __restrict__ A,
    const unsigned short* __restrict__ Bt,
    const float* __restrict__ bias,
    unsigned short* __restrict__ outA,
    int K, int Nc) {
  __shared__ unsigned short As[128 * 32];
  __shared__ unsigned short Bs[128 * 32];
  const int tid = threadIdx.x;
  const int wave = tid >> 6, lane = tid & 63;
  const int wr = wave >> 1, wc = wave & 1;
  const int lr = lane & 15, lh = lane >> 4;
  const long row0 = (long)blockIdx.x * 128;
  const int col0 = blockIdx.y * 128;

  f32x4 acc[4][4];
#pragma unroll
  for (int m = 0; m < 4; ++m)
#pragma unroll
    for (int n = 0; n < 4; ++n) acc[m][n] = (f32x4){0.f, 0.f, 0.f, 0.f};

  const int nk = K >> 5;
  for (int kt = 0; kt < nk; ++kt) {
    const int k0 = kt << 5;
#pragma unroll
    for (int i = 0; i < 2; ++i) {
      int c = i * 256 + wave * 64 + lane;
      int r = c >> 2, k8 = (c & 3) * 8;
      gload_lds16(A + (row0 + r) * K + k0 + k8, &As[(i * 256 + wave * 64) * 8]);
      gload_lds16(Bt + (long)(col0 + r) * K + k0 + k8,
                  &Bs[(i * 256 + wave * 64) * 8]);
    }
    __syncthreads();
    bf16x8 af[4], bfr[4];
#pragma unroll
    for (int m = 0; m < 4; ++m)
      af[m] = *(const bf16x8*)&As[(wr * 64 + m * 16 + lr) * 32 + lh * 8];
#pragma unroll
    for (int n = 0; n < 4; ++n)
      bfr[n] = *(const bf16x8*)&Bs[(wc * 64 + n * 16 + lr) * 32 + lh * 8];
#pragma unroll
    for (int m = 0; m < 4; ++m)
#pragma unroll
      for (int n = 0; n < 4; ++n)
        acc[m][n] =
            __builtin_amdgcn_mfma_f32_16x16x32_bf16(af[m], bfr[n], acc[m][n], 0, 0, 0);
    __syncthreads();
  }

  float bv[4];
#pragma unroll
  for (int n = 0; n < 4; ++n) bv[n] = bias[col0 + wc * 64 + n * 16 + lr];
#pragma unroll
  for (int m = 0; m < 4; ++m) {
    long rbase = row0 + wr * 64 + m * 16 + lh * 4;
#pragma unroll
    for (int r = 0; r < 4; ++r) {
      long rr = rbase + r;
#pragma unroll
      for (int n = 0; n < 4; ++n) {
        int cc = col0 + wc * 64 + n * 16 + lr;
        float v = acc[m][n][r] + bv[n];
        outA[rr * Nc + cc] = f2bf(fmaxf(v, 0.f));
      }
    }
  }
}

#define MFMA16(MQ, N0)                                                       \
  _Pragma("unroll") for (int m = 0; m < 4; ++m)                              \
  _Pragma("unroll") for (int n = 0; n < 2; ++n)                              \
  _Pragma("unroll") for (int kk = 0; kk < 2; ++kk)                           \
      acc[(MQ)*4 + m][(N0) + n] = __builtin_amdgcn_mfma_f32_16x16x32_bf16(   \
          a[m][kk], b[(N0) + n][kk], acc[(MQ)*4 + m][(N0) + n], 0, 0, 0);

// 256x256 tile, BK=64, 8 waves (2Mx4N), double-buffered LDS halves with
// st_16x32 swizzle, 4-phase/K-tile schedule, counted vmcnt (8-phase template).
__global__ __launch_bounds__(512) void gemm256(
    const unsigned short* __restrict__ A, long aZ,
    const unsigned short* __restrict__ Bt, long bZ,
    const float* __restrict__ bias, long biasZ,
    float* __restrict__ outF,
    unsigned short* __restrict__ outA, long cZ,
    int K, int Nc,
    const unsigned short* __restrict__ W2b,  // head weights [P][256] or null
    const float* __restrict__ Sb2, const int* __restrict__ y,
    const int* __restrict__ pairs, int r0,
    float* __restrict__ outR, float* __restrict__ outS,
    float* __restrict__ outM) {
  __shared__ unsigned short lds[65536];  // 128 KiB: A 2buf x 2half x 16KB, then B
  const int z = blockIdx.z;
  A += (long)z * aZ;
  Bt += (long)z * bZ;
  bias += (long)z * biasZ;
  if (outA) outA += (long)z * cZ;

  const int tid = threadIdx.x;
  const int wave = tid >> 6, lane = tid & 63;
  const int wm = wave >> 2, wn = wave & 3;
  const int lr = lane & 15, lh = lane >> 4;
  const long brow = (long)blockIdx.x * 256;
  const int bcol = blockIdx.y * 256;
  const int nk = K >> 6;

  // stage addressing (pre-swizzled global source, linear LDS dest)
  const int lsrc = lane ^ (((lane >> 5) & 1) << 1);
  const int srow = lsrc >> 3;         // 0..7 row within 8-row stripe
  const int skel = (lsrc & 7) * 8;    // k-elem offset of this lane's 16B
  // swizzled read column (elems): byte ^= ((byte>>9)&1)<<5  ->  per-lane const
  const int acol = (lh * 8) ^ (((lr >> 2) & 1) << 4);

  f32x4 acc[8][4];
#pragma unroll
  for (int m = 0; m < 8; ++m)
#pragma unroll
    for (int n = 0; n < 4; ++n) acc[m][n] = (f32x4){0.f, 0.f, 0.f, 0.f};

  // half-stage order per K-tile: slot 0=B-h0, 1=B-h1, 2=A-h0, 3=A-h1
  auto STAGE = [&](int S) {
    if (S >= nk * 4) return;
    const int tile = S >> 2, slot = S & 3, buf = tile & 1, half = slot & 1;
    const int k0 = tile << 6;
    const unsigned short* src;
    long rb;
    int lbase;
    if (slot >= 2) {
      src = A;  rb = brow + half * 128;  lbase = buf * 16384 + half * 8192;
    } else {
      src = Bt; rb = bcol + half * 128;  lbase = 32768 + buf * 16384 + half * 8192;
    }
#pragma unroll
    for (int i = 0; i < 2; ++i) {
      int c = wave * 2 + i;
      gload_lds16(src + (rb + c * 8 + srow) * K + k0 + skel,
                  &lds[lbase + c * 512]);
    }
  };

  // prologue: stage tile0 (4 halves) + 3 halves of tile1; wait tile0 landed
#pragma unroll
  for (int S0 = 0; S0 < 7; ++S0) STAGE(S0);
  asm volatile("s_waitcnt vmcnt(6)" ::: "memory");
  __builtin_amdgcn_s_barrier();

  bf16x8 a[4][2], b[4][2];
  int S = 7;
  for (int t = 0; t < nk; ++t) {
    const int buf = t & 1;
    const int ab = buf * 16384 + wm * 8192;
    const int bb = 32768 + buf * 16384 + (wn >> 1) * 8192 + (wn & 1) * 64 * 64;
    // ---- phase 0: read A-quad0 + all B; stage; MFMA q(0, n0-1)
#pragma unroll
    for (int m = 0; m < 4; ++m) {
      a[m][0] = *(const bf16x8*)&lds[ab + (m * 16 + lr) * 64 + acol];
      a[m][1] = *(const bf16x8*)&lds[ab + (m * 16 + lr) * 64 + 32 + acol];
    }
#pragma unroll
    for (int n = 0; n < 4; ++n) {
      b[n][0] = *(const bf16x8*)&lds[bb + (n * 16 + lr) * 64 + acol];
      b[n][1] = *(const bf16x8*)&lds[bb + (n * 16 + lr) * 64 + 32 + acol];
    }
    STAGE(S++);
    __builtin_amdgcn_s_barrier();
    __builtin_amdgcn_s_setprio(1);
    MFMA16(0, 0)
    __builtin_amdgcn_s_setprio(0);
    __builtin_amdgcn_s_barrier();
    // ---- phase 1: stage; MFMA q(0, n2-3)
    STAGE(S++);
    __builtin_amdgcn_s_barrier();
    __builtin_amdgcn_s_setprio(1);
    MFMA16(0, 2)
    __builtin_amdgcn_s_setprio(0);
    __builtin_amdgcn_s_barrier();
    // ---- phase 2: read A-quad1; stage; MFMA q(1, n2-3)
#pragma unroll
    for (int m = 0; m < 4; ++m) {
      a[m][0] = *(const bf16x8*)&lds[ab + ((m + 4) * 16 + lr) * 64 + acol];
      a[m][1] = *(const bf16x8*)&lds[ab + ((m + 4) * 16 + lr) * 64 + 32 + acol];
    }
    STAGE(S++);
    __builtin_amdgcn_s_barrier();
    __builtin_amdgcn_s_setprio(1);
    MFMA16(1, 2)
    __builtin_amdgcn_s_setprio(0);
    __builtin_amdgcn_s_barrier();
    // ---- phase 3: stage; counted vmcnt (next tile landed); MFMA q(1, n0-1)
    STAGE(S++);
    if (t < nk - 2)
      asm volatile("s_waitcnt vmcnt(6)" ::: "memory");
    else
      asm volatile("s_waitcnt vmcnt(0)" ::: "memory");
    __builtin_amdgcn_s_barrier();
    __builtin_amdgcn_s_setprio(1);
    MFMA16(1, 0)
    __builtin_amdgcn_s_setprio(0);
    __builtin_amdgcn_s_barrier();
  }

  if (!W2b) {
    float bv[4];
#pragma unroll
    for (int n = 0; n < 4; ++n) bv[n] = bias[bcol + wn * 64 + n * 16 + lr];
#pragma unroll
    for (int m = 0; m < 8; ++m) {
      long rbase = brow + wm * 128 + m * 16 + lh * 4;
#pragma unroll
      for (int r = 0; r < 4; ++r) {
        long rr = rbase + r;
#pragma unroll
        for (int n = 0; n < 4; ++n) {
          int cc = bcol + wn * 64 + n * 16 + lr;
          float v = acc[m][n][r] + bv[n];
          if (outF) outF[rr * Nc + cc] = v;
          if (outA) outA[rr * Nc + cc] = f2bf(fmaxf(v, 0.f));
        }
      }
    }
  } else {
    // fused 256->1 head: logit = sum relu(h+b)*w2; sigmoid/clip/ratio/mask
    const unsigned short* w2 = W2b + z * 256;
    float bv[4], w2v[4];
#pragma unroll
    for (int n = 0; n < 4; ++n) {
      int cc = wn * 64 + n * 16 + lr;
      bv[n] = bias[cc];
      w2v[n] = bf2f(w2[cc]);
    }
    float* part = (float*)lds;  // [4][256], aliases dead GEMM tiles
    __syncthreads();
#pragma unroll
    for (int m = 0; m < 8; ++m) {
#pragma unroll
      for (int r = 0; r < 4; ++r) {
        float s = 0.f;
#pragma unroll
        for (int n = 0; n < 4; ++n)
          s += fmaxf(acc[m][n][r] + bv[n], 0.f) * w2v[n];
#pragma unroll
        for (int off = 1; off < 16; off <<= 1) s += __shfl_xor(s, off);
        if (lr == 0) part[wn * 256 + wm * 128 + m * 16 + lh * 4 + r] = s;
      }
    }
    __syncthreads();
    if (tid < 256) {
      float logit = part[tid] + part[256 + tid] + part[512 + tid] +
                    part[768 + tid] + Sb2[z];
      float s = 1.f / (1.f + expf(-logit));
      s = fmaxf(s, 1e-9f);
      float rr = (1.f - s) / s;
      long n = (long)r0 + brow + tid;
      int yv = y[n];
      float mf = (yv == pairs[z * 2] || yv == pairs[z * 2 + 1]) ? 1.f : 0.f;
      outR[(long)z * NE + n] = rr * mf;
      outS[(long)z * NE + n] = s * mf;
      outM[(long)z * NE + n] = mf;
    }
  }
}

extern "C" void kernel_launch(void* const* d_in, const int* in_sizes, int n_in,
                              void* d_out, int out_size, void* d_ws, size_t ws_size,
                              hipStream_t stream) {
  const float* x   = (const float*)d_in[0];
  const int*   y   = (const int*)d_in[1];
  const int*   prs = (const int*)d_in[2];
  const float* W0  = (const float*)d_in[3];
  const float* b0  = (const float*)d_in[4];
  const float* W1  = (const float*)d_in[5];
  const float* b1  = (const float*)d_in[6];
  const float* W2  = (const float*)d_in[7];
  const float* b2  = (const float*)d_in[8];
  const float* SW0 = (const float*)d_in[9];
  const float* Sb0 = (const float*)d_in[10];
  const float* SW1 = (const float*)d_in[11];
  const float* Sb1 = (const float*)d_in[12];
  const float* SW2 = (const float*)d_in[13];
  const float* Sb2 = (const float*)d_in[14];

  uint8_t* ws = (uint8_t*)d_ws;
  size_t off = 0;
  auto take = [&](size_t bytes) -> void* {
    void* ptr = ws + off;
    off = (off + bytes + 255) & ~(size_t)255;
    return ptr;
  };
  unsigned short* W0t  = (unsigned short*)take((size_t)64 * 512 * 2);
  unsigned short* W1t  = (unsigned short*)take((size_t)512 * 512 * 2);
  unsigned short* W2t  = (unsigned short*)take((size_t)512 * 512 * 2);
  unsigned short* SW0t = (unsigned short*)take((size_t)3 * 512 * 512 * 2);
  unsigned short* SW1t = (unsigned short*)take((size_t)3 * 256 * 512 * 2);
  unsigned short* SW2b = (unsigned short*)take((size_t)3 * 256 * 2);
  unsigned short* Xb   = (unsigned short*)take((size_t)NE * 64 * 2);
  unsigned short* A3   = (unsigned short*)take((size_t)3 * CHUNK * 512 * 2);
  unsigned short* T0   = A3;                       // alias: dead before SW0 writes
  unsigned short* T1   = A3 + (size_t)CHUNK * 512;
  unsigned short* bufR = (unsigned short*)take((size_t)CHUNK * 512 * 2);

  float* out   = (float*)d_out;
  float* outRe = out;
  float* outR  = out + (size_t)NE * 512;
  float* outS  = outR + (size_t)3 * NE;
  float* outM  = outS + (size_t)3 * NE;

  transpose_cvt<<<dim3(128, 1), 256, 0, stream>>>(W0, W0t, 64, 512);
  transpose_cvt<<<dim3(1024, 1), 256, 0, stream>>>(W1, W1t, 512, 512);
  transpose_cvt<<<dim3(1024, 1), 256, 0, stream>>>(W2, W2t, 512, 512);
  transpose_cvt<<<dim3(1024, 3), 256, 0, stream>>>(SW0, SW0t, 512, 512);
  transpose_cvt<<<dim3(512, 3), 256, 0, stream>>>(SW1, SW1t, 512, 256);
  transpose_cvt<<<dim3(1, 3), 256, 0, stream>>>(SW2, SW2b, 256, 1);
  relu_cvt_x<<<dim3(NE * 64 / 4 / 256), 256, 0, stream>>>((const float4*)x,
                                                          (ushort4*)Xb);

  for (int c = 0; c < NE / CHUNK; ++c) {
    size_t r0 = (size_t)c * CHUNK;
    // L0 (K=64): m97 kernel
    gemm_bf16<<<dim3(CHUNK / 128, 4), 256, 0, stream>>>(Xb + r0 * 64, W0t, b0,
                                                        T0, 64, 512);
    // L1: T0 -> T1
    gemm256<<<dim3(CHUNK / 256, 2, 1), 512, 0, stream>>>(
        T0, 0, W1t, 0, b1, 0, nullptr, T1, 0, 512, 512,
        nullptr, nullptr, nullptr, nullptr, 0, nullptr, nullptr, nullptr);
    // L2: T1 -> (repr fp32, bufR bf16)
    gemm256<<<dim3(CHUNK / 256, 2, 1), 512, 0, stream>>>(
        T1, 0, W2t, 0, b2, 0, outRe + r0 * 512, bufR, 0, 512, 512,
        nullptr, nullptr, nullptr, nullptr, 0, nullptr, nullptr, nullptr);
    // SW0 batched over p: bufR -> A3[p]
    gemm256<<<dim3(CHUNK / 256, 2, 3), 512, 0, stream>>>(
        bufR, 0, SW0t, (long)512 * 512, Sb0, 512, nullptr, A3,
        (long)CHUNK * 512, 512, 512,
        nullptr, nullptr, nullptr, nullptr, 0, nullptr, nullptr, nullptr);
    // SW1 + fused head, batched over p
    gemm256<<<dim3(CHUNK / 256, 1, 3), 512, 0, stream>>>(
        A3, (long)CHUNK * 512, SW1t, (long)256 * 512, Sb1, 256, nullptr,
        nullptr, 0, 512, 256,
        SW2b, Sb2, y, prs, (int)r0, outR, outS, outM);
  }
}